// Round 20
// baseline (68.282 us; speedup 1.0000x reference)
//
#include <hip/hip_runtime.h>
#include <hip/hip_bf16.h>

typedef __attribute__((ext_vector_type(8))) short bf16x8;
typedef __attribute__((ext_vector_type(4))) float f32x4;

__device__ __forceinline__ ushort f2bf(float x) {
  unsigned u = __float_as_uint(x);
  u = (u + 0x7FFFu + ((u >> 16) & 1u)) >> 16;
  return (ushort)u;
}

// Pack K (f32 [256][1024]) into MFMA-fragment order:
// chunk c = (otile 0..63, ks 0..7, lane 0..63); chunk holds 8 bf16:
//   o = otile*16 + (lane&15), k = ks*32 + (lane>>4)*8 + e
__global__ void WV_kconv(const float* __restrict__ K, ushort* __restrict__ KtP) {
  int c = blockIdx.x * 256 + threadIdx.x;  // 0..32767
  int otile = c >> 9, ks = (c >> 6) & 7, lane = c & 63;
  int o = otile * 16 + (lane & 15);
  int kb = ks * 32 + (lane >> 4) * 8;
  bf16x8 w;
  #pragma unroll
  for (int e = 0; e < 8; ++e)
    w[e] = (short)f2bf(K[(size_t)(kb + e) * 1024 + o]);
  *reinterpret_cast<bf16x8*>(KtP + (size_t)c * 8) = w;
}

// Block (b,h): h = i-QUARTER (64 rows) -> 32 KB LDS -> 2 blocks/CU,
// 4 waves/SIMD. 8 waves; wave owns o-strip of 128.
// R20 vs R19: ks-loop unrolled 2-wide with NAMED ping-pong buffers B0/B1
// (even half computes B0 / loads B1; odd half computes B1 / reloads B0).
// Kills the 16 v_mov Bc<-Bn copies + halves the branch count per iter
// (R19 post-mortem: VALUBusy 36% > MfmaUtil 25%, copies were the largest
// inner-loop VALU block). Same 32-reg B footprint; cross-og prefetch kept.
__global__ __launch_bounds__(512, 2) void WV_main(
    const float* __restrict__ A, const ushort* __restrict__ KtP,
    float* __restrict__ out) {
  __shared__ short As[64 * 256];  // 32 KB
  const int bh = blockIdx.x;
  const int b = bh >> 2, h = bh & 3;
  const float* Ah = A + (size_t)b * 65536 + (size_t)h * 16384;
  const int t = threadIdx.x;

  // ---- stage 64 rows: fp32 -> bf16, swizzle byte ^= (row&7)<<4 ----
  #pragma unroll 1
  for (int it = 0; it < 4; ++it) {
    int c = it * 512 + t;  // chunk of 8 floats
    int m = c >> 5;        // local row 0..63
    int s = c & 31;        // 16B slot within row
    const float4* p = reinterpret_cast<const float4*>(Ah) + c * 2;
    float4 v0 = p[0], v1 = p[1];
    bf16x8 w;
    w[0] = (short)f2bf(v0.x); w[1] = (short)f2bf(v0.y);
    w[2] = (short)f2bf(v0.z); w[3] = (short)f2bf(v0.w);
    w[4] = (short)f2bf(v1.x); w[5] = (short)f2bf(v1.y);
    w[6] = (short)f2bf(v1.z); w[7] = (short)f2bf(v1.w);
    int byteoff = m * 512 + ((s * 16) ^ ((m & 7) << 4));
    *reinterpret_cast<bf16x8*>(reinterpret_cast<char*>(As) + byteoff) = w;
  }
  __syncthreads();

  const int wave = t >> 6, lane = t & 63;
  const int lo = lane & 15;   // col within tile (B,D) / row (A)
  const int hi = lane >> 4;   // 0..3
  const int wob = wave * 128;

  // B ping-pong buffers, live across og for the cross-og prefetch.
  bf16x8 B0[4], B1[4];
  #pragma unroll
  for (int ot = 0; ot < 4; ++ot)
    B0[ot] = *reinterpret_cast<const bf16x8*>(
        KtP + ((size_t)((wave * 8 + ot) * 8 + 0) * 64 + lane) * 8);

  #pragma unroll 1
  for (int og = 0; og < 2; ++og) {
    const int otb = wave * 8 + og * 4;  // o-tile base
    float oseg[4] = {0.f, 0.f, 0.f, 0.f};

    f32x4 acc[4][4];
    #pragma unroll
    for (int a1 = 0; a1 < 4; ++a1)
      #pragma unroll
      for (int a2 = 0; a2 < 4; ++a2)
        acc[a1][a2] = (f32x4){0.f, 0.f, 0.f, 0.f};

    #pragma unroll 1
    for (int kp = 0; kp < 4; ++kp) {
      const int ks0 = kp * 2, ks1 = kp * 2 + 1;
      // prefetch odd-half B fragments
      #pragma unroll
      for (int ot = 0; ot < 4; ++ot)
        B1[ot] = *reinterpret_cast<const bf16x8*>(
            KtP + ((size_t)((otb + ot) * 8 + ks1) * 64 + lane) * 8);
      // compute even half from B0
      __builtin_amdgcn_s_setprio(1);
      #pragma unroll
      for (int itl = 0; itl < 4; ++itl) {
        int m = itl * 16 + lo;
        int byteoff = m * 512 + ((ks0 * 64 + hi * 16) ^ ((m & 7) << 4));
        bf16x8 Af = *reinterpret_cast<const bf16x8*>(
            reinterpret_cast<char*>(As) + byteoff);
        #pragma unroll
        for (int ot = 0; ot < 4; ++ot)
          acc[itl][ot] = __builtin_amdgcn_mfma_f32_16x16x32_bf16(
              Af, B0[ot], acc[itl][ot], 0, 0, 0);
      }
      __builtin_amdgcn_s_setprio(0);
      // reload B0: next even ks, or og=1's ks=0 at the og boundary
      if (kp < 3) {
        #pragma unroll
        for (int ot = 0; ot < 4; ++ot)
          B0[ot] = *reinterpret_cast<const bf16x8*>(
              KtP + ((size_t)((otb + ot) * 8 + ks0 + 2) * 64 + lane) * 8);
      } else if (og == 0) {
        #pragma unroll
        for (int ot = 0; ot < 4; ++ot)
          B0[ot] = *reinterpret_cast<const bf16x8*>(
              KtP + ((size_t)((wave * 8 + 4 + ot) * 8 + 0) * 64 + lane) * 8);
      }
      // compute odd half from B1
      __builtin_amdgcn_s_setprio(1);
      #pragma unroll
      for (int itl = 0; itl < 4; ++itl) {
        int m = itl * 16 + lo;
        int byteoff = m * 512 + ((ks1 * 64 + hi * 16) ^ ((m & 7) << 4));
        bf16x8 Af = *reinterpret_cast<const bf16x8*>(
            reinterpret_cast<char*>(As) + byteoff);
        #pragma unroll
        for (int ot = 0; ot < 4; ++ot)
          acc[itl][ot] = __builtin_amdgcn_mfma_f32_16x16x32_bf16(
              Af, B1[ot], acc[itl][ot], 0, 0, 0);
      }
      __builtin_amdgcn_s_setprio(0);
    }

    // epilogue: weights K[i0..i0+3][o(lane)] from KtP packed layout.
    // i0 = h*64+itl*16+hi*4 = kse*32+g*8+e with kse = h*2+(itl>>1),
    // g = (itl&1)*2+(hi>>1), e = (hi&1)*4.
    #pragma unroll
    for (int itl = 0; itl < 4; ++itl) {
      const int kse = h * 2 + (itl >> 1);
      const int g = (itl & 1) * 2 + (hi >> 1);
      const int e = (hi & 1) * 4;
      #pragma unroll
      for (int ot = 0; ot < 4; ++ot) {
        const ushort* wp = KtP +
            ((size_t)((otb + ot) * 8 + kse) * 64 + lo + g * 16) * 8 + e;
        ushort4 wv = *reinterpret_cast<const ushort4*>(wp);
        f32x4 a = acc[itl][ot];
        float s = __uint_as_float((unsigned)wv.x << 16) * a[0]
                + __uint_as_float((unsigned)wv.y << 16) * a[1]
                + __uint_as_float((unsigned)wv.z << 16) * a[2]
                + __uint_as_float((unsigned)wv.w << 16) * a[3];
        s += __shfl_xor(s, 16);
        s += __shfl_xor(s, 32);
        oseg[ot] += s;
      }
    }

    if (lane < 16) {
      #pragma unroll
      for (int ot = 0; ot < 4; ++ot)
        atomicAdd(&out[(size_t)b * 1024 + wob + og * 64 + ot * 16 + lane],
                  oseg[ot]);
    }
  }
}

extern "C" void kernel_launch(void* const* d_in, const int* in_sizes, int n_in,
                              void* d_out, int out_size, void* d_ws, size_t ws_size,
                              hipStream_t stream) {
  const float* A = (const float*)d_in[0];   // (256,256,256) f32
  const float* K = (const float*)d_in[1];   // (256,1024)   f32
  float* out = (float*)d_out;               // (256,1024)   f32
  ushort* KtP = (ushort*)d_ws;              // packed (64,8,64,8) bf16
  hipMemsetAsync(d_out, 0, (size_t)out_size * sizeof(float), stream);
  WV_kconv<<<128, 256, 0, stream>>>(K, KtP);
  WV_main<<<1024, 512, 0, stream>>>(A, KtP, out);
}

// Round 21
// 62.483 us; speedup vs baseline: 1.0928x; 1.0928x over previous
//
#include <hip/hip_runtime.h>
#include <hip/hip_bf16.h>

typedef __attribute__((ext_vector_type(8))) short bf16x8;
typedef __attribute__((ext_vector_type(4))) float f32x4;

__device__ __forceinline__ ushort f2bf(float x) {
  union { __hip_bfloat16 h; ushort u; } c;
  c.h = __float2bfloat16(x);  // RTNE, same bits as manual twiddle
  return c.u;
}

// Pack K (f32 [256][1024]) into MFMA-fragment order, DUAL dtype:
// chunk c = (otile 0..63, ks 0..7, lane 0..63); chunk holds 8 elems:
//   o = otile*16 + (lane&15), k = ks*32 + (lane>>4)*8 + e
// KtP: bf16 (MFMA B-operand).  KtW: f32 same layout (epilogue weights —
// kills the 128 lshl bf16->f32 converts per wave, R20 post-mortem).
__global__ void WV_kconv(const float* __restrict__ K, ushort* __restrict__ KtP,
                         float* __restrict__ KtW) {
  int c = blockIdx.x * 256 + threadIdx.x;  // 0..32767
  int otile = c >> 9, ks = (c >> 6) & 7, lane = c & 63;
  int o = otile * 16 + (lane & 15);
  int kb = ks * 32 + (lane >> 4) * 8;
  float kf[8];
  bf16x8 w;
  #pragma unroll
  for (int e = 0; e < 8; ++e) {
    kf[e] = K[(size_t)(kb + e) * 1024 + o];
    w[e] = (short)f2bf(kf[e]);
  }
  *reinterpret_cast<bf16x8*>(KtP + (size_t)c * 8) = w;
  float4* dst = reinterpret_cast<float4*>(KtW + (size_t)c * 8);
  dst[0] = (float4){kf[0], kf[1], kf[2], kf[3]};
  dst[1] = (float4){kf[4], kf[5], kf[6], kf[7]};
}

// Block (b,h): h = i-QUARTER (64 rows) -> 32 KB LDS -> 2 blocks/CU,
// 4 waves/SIMD. 8 waves; wave owns o-strip of 128.
// R21 = R19 structure (best measured 54.8us; 64+64 regs at the wave-
// capacity boundary) + f32 epilogue weights (KtW) + cvt_pk-friendly
// staging casts. Zero intended register delta; (512,2) cap backstops.
__global__ __launch_bounds__(512, 2) void WV_main(
    const float* __restrict__ A, const ushort* __restrict__ KtP,
    const float* __restrict__ KtW, float* __restrict__ out) {
  __shared__ short As[64 * 256];  // 32 KB
  const int bh = blockIdx.x;
  const int b = bh >> 2, h = bh & 3;
  const float* Ah = A + (size_t)b * 65536 + (size_t)h * 16384;
  const int t = threadIdx.x;

  // ---- stage 64 rows: fp32 -> bf16, swizzle byte ^= (row&7)<<4 ----
  #pragma unroll 1
  for (int it = 0; it < 4; ++it) {
    int c = it * 512 + t;  // chunk of 8 floats
    int m = c >> 5;        // local row 0..63
    int s = c & 31;        // 16B slot within row
    const float4* p = reinterpret_cast<const float4*>(Ah) + c * 2;
    float4 v0 = p[0], v1 = p[1];
    bf16x8 w;
    w[0] = (short)f2bf(v0.x); w[1] = (short)f2bf(v0.y);
    w[2] = (short)f2bf(v0.z); w[3] = (short)f2bf(v0.w);
    w[4] = (short)f2bf(v1.x); w[5] = (short)f2bf(v1.y);
    w[6] = (short)f2bf(v1.z); w[7] = (short)f2bf(v1.w);
    int byteoff = m * 512 + ((s * 16) ^ ((m & 7) << 4));
    *reinterpret_cast<bf16x8*>(reinterpret_cast<char*>(As) + byteoff) = w;
  }
  __syncthreads();

  const int wave = t >> 6, lane = t & 63;
  const int lo = lane & 15;   // col within tile (B,D) / row (A)
  const int hi = lane >> 4;   // 0..3
  const int wob = wave * 128;

  #pragma unroll 1
  for (int og = 0; og < 2; ++og) {
    float oseg[4] = {0.f, 0.f, 0.f, 0.f};
    const int otb = wave * 8 + og * 4;  // o-tile base

    f32x4 acc[4][4];
    #pragma unroll
    for (int a1 = 0; a1 < 4; ++a1)
      #pragma unroll
      for (int a2 = 0; a2 < 4; ++a2)
        acc[a1][a2] = (f32x4){0.f, 0.f, 0.f, 0.f};

    // prologue: load ks=0 fragments
    bf16x8 Bc[4];
    #pragma unroll
    for (int ot = 0; ot < 4; ++ot)
      Bc[ot] = *reinterpret_cast<const bf16x8*>(
          KtP + ((size_t)((otb + ot) * 8 + 0) * 64 + lane) * 8);

    #pragma unroll 1
    for (int ks = 0; ks < 8; ++ks) {
      bf16x8 Bn[4];
      if (ks < 7) {  // prefetch next ks (wave-uniform branch)
        #pragma unroll
        for (int ot = 0; ot < 4; ++ot)
          Bn[ot] = *reinterpret_cast<const bf16x8*>(
              KtP + ((size_t)((otb + ot) * 8 + ks + 1) * 64 + lane) * 8);
      }
      const int kk = ks * 32 + hi * 8;
      __builtin_amdgcn_s_setprio(1);
      #pragma unroll
      for (int itl = 0; itl < 4; ++itl) {
        int m = itl * 16 + lo;
        int byteoff = m * 512 + ((kk * 2) ^ ((m & 7) << 4));
        bf16x8 Af = *reinterpret_cast<const bf16x8*>(
            reinterpret_cast<char*>(As) + byteoff);
        #pragma unroll
        for (int ot = 0; ot < 4; ++ot)
          acc[itl][ot] = __builtin_amdgcn_mfma_f32_16x16x32_bf16(
              Af, Bc[ot], acc[itl][ot], 0, 0, 0);
      }
      __builtin_amdgcn_s_setprio(0);
      if (ks < 7) {
        #pragma unroll
        for (int ot = 0; ot < 4; ++ot) Bc[ot] = Bn[ot];
      }
    }

    // epilogue: f32 weights from KtW (same chunk layout as KtP).
    // i0 = h*64+itl*16+hi*4 = kse*32+g*8+e with kse = h*2+(itl>>1),
    // g = (itl&1)*2+(hi>>1), e = (hi&1)*4.
    #pragma unroll
    for (int itl = 0; itl < 4; ++itl) {
      const int kse = h * 2 + (itl >> 1);
      const int g = (itl & 1) * 2 + (hi >> 1);
      const int e = (hi & 1) * 4;
      #pragma unroll
      for (int ot = 0; ot < 4; ++ot) {
        const float* wp = KtW +
            ((size_t)((otb + ot) * 8 + kse) * 64 + lo + g * 16) * 8 + e;
        float4 wv = *reinterpret_cast<const float4*>(wp);
        f32x4 a = acc[itl][ot];
        float s = wv.x * a[0] + wv.y * a[1] + wv.z * a[2] + wv.w * a[3];
        s += __shfl_xor(s, 16);
        s += __shfl_xor(s, 32);
        oseg[ot] += s;
      }
    }

    if (lane < 16) {
      #pragma unroll
      for (int ot = 0; ot < 4; ++ot)
        atomicAdd(&out[(size_t)b * 1024 + wob + og * 64 + ot * 16 + lane],
                  oseg[ot]);
    }
  }
}

extern "C" void kernel_launch(void* const* d_in, const int* in_sizes, int n_in,
                              void* d_out, int out_size, void* d_ws, size_t ws_size,
                              hipStream_t stream) {
  const float* A = (const float*)d_in[0];   // (256,256,256) f32
  const float* K = (const float*)d_in[1];   // (256,1024)   f32
  float* out = (float*)d_out;               // (256,1024)   f32
  ushort* KtP = (ushort*)d_ws;              // packed (64,8,64,8) bf16, 512 KB
  float* KtW = (float*)((char*)d_ws + (1 << 19));  // packed f32, 1 MB
  hipMemsetAsync(d_out, 0, (size_t)out_size * sizeof(float), stream);
  WV_kconv<<<128, 256, 0, stream>>>(K, KtP, KtW);
  WV_main<<<1024, 512, 0, stream>>>(A, KtP, KtW, out);
}

// Round 22
// 57.195 us; speedup vs baseline: 1.1938x; 1.0925x over previous
//
#include <hip/hip_runtime.h>
#include <hip/hip_bf16.h>

typedef __attribute__((ext_vector_type(8))) short bf16x8;
typedef __attribute__((ext_vector_type(4))) float f32x4;

__device__ __forceinline__ ushort f2bf(float x) {
  unsigned u = __float_as_uint(x);
  u = (u + 0x7FFFu + ((u >> 16) & 1u)) >> 16;
  return (ushort)u;
}

// Pack K (f32 [256][1024]) into MFMA-fragment order:
// chunk c = (otile 0..63, ks 0..7, lane 0..63); chunk holds 8 bf16:
//   o = otile*16 + (lane&15), k = ks*32 + (lane>>4)*8 + e
__global__ void WV_kconv(const float* __restrict__ K, ushort* __restrict__ KtP) {
  int c = blockIdx.x * 256 + threadIdx.x;  // 0..32767
  int otile = c >> 9, ks = (c >> 6) & 7, lane = c & 63;
  int o = otile * 16 + (lane & 15);
  int kb = ks * 32 + (lane >> 4) * 8;
  bf16x8 w;
  #pragma unroll
  for (int e = 0; e < 8; ++e)
    w[e] = (short)f2bf(K[(size_t)(kb + e) * 1024 + o]);
  *reinterpret_cast<bf16x8*>(KtP + (size_t)c * 8) = w;
}

// Block (b,h): h = i-QUARTER (64 rows) -> 32 KB LDS -> 2 blocks/CU,
// 4 waves/SIMD. 8 waves; wave owns o-strip of 128.
// R22 vs R19 (two zero-register fixes):
//  1. Swizzle (m&7)<<4 -> (m&7)<<6. The Af read is 16 rows x 4 hi-cols;
//     old swizzle collided hi (bits 0-1 of 16B-slot) with m&7 (bits 0-2)
//     -> 8-way bank conflict (2.94x, largest pipe; SQ_LDS_BANK_CONFLICT
//     clipped at 2^21 every round). New: slot = ks*4 + (hi ^ (m&7)<<2),
//     disjoint bits -> all 32 slots, 2-way = free.
//  2. ks unrolled 2-wide with B0/B1 SCOPED INSIDE og (no cross-og
//     liveness, unlike R20) -> kills 16 v_mov copies/iter at 0 regs.
__global__ __launch_bounds__(512, 2) void WV_main(
    const float* __restrict__ A, const ushort* __restrict__ KtP,
    float* __restrict__ out) {
  __shared__ short As[64 * 256];  // 32 KB
  const int bh = blockIdx.x;
  const int b = bh >> 2, h = bh & 3;
  const float* Ah = A + (size_t)b * 65536 + (size_t)h * 16384;
  const int t = threadIdx.x;

  // ---- stage 64 rows: fp32 -> bf16, swizzle byte ^= (row&7)<<6 ----
  #pragma unroll 1
  for (int it = 0; it < 4; ++it) {
    int c = it * 512 + t;  // chunk of 8 floats
    int m = c >> 5;        // local row 0..63
    int s = c & 31;        // 16B slot within row
    const float4* p = reinterpret_cast<const float4*>(Ah) + c * 2;
    float4 v0 = p[0], v1 = p[1];
    bf16x8 w;
    w[0] = (short)f2bf(v0.x); w[1] = (short)f2bf(v0.y);
    w[2] = (short)f2bf(v0.z); w[3] = (short)f2bf(v0.w);
    w[4] = (short)f2bf(v1.x); w[5] = (short)f2bf(v1.y);
    w[6] = (short)f2bf(v1.z); w[7] = (short)f2bf(v1.w);
    int byteoff = m * 512 + ((s * 16) ^ ((m & 7) << 6));
    *reinterpret_cast<bf16x8*>(reinterpret_cast<char*>(As) + byteoff) = w;
  }
  __syncthreads();

  const int wave = t >> 6, lane = t & 63;
  const int lo = lane & 15;   // col within tile (B,D) / row (A)
  const int hi = lane >> 4;   // 0..3
  const int wob = wave * 128;

  #pragma unroll 1
  for (int og = 0; og < 2; ++og) {
    float oseg[4] = {0.f, 0.f, 0.f, 0.f};
    const int otb = wave * 8 + og * 4;  // o-tile base

    f32x4 acc[4][4];
    #pragma unroll
    for (int a1 = 0; a1 < 4; ++a1)
      #pragma unroll
      for (int a2 = 0; a2 < 4; ++a2)
        acc[a1][a2] = (f32x4){0.f, 0.f, 0.f, 0.f};

    bf16x8 B0[4], B1[4];  // scoped to og: no cross-og liveness
    #pragma unroll
    for (int ot = 0; ot < 4; ++ot)
      B0[ot] = *reinterpret_cast<const bf16x8*>(
          KtP + ((size_t)((otb + ot) * 8 + 0) * 64 + lane) * 8);

    #pragma unroll 1
    for (int kp = 0; kp < 4; ++kp) {
      const int ks0 = kp * 2, ks1 = kp * 2 + 1;
      // load odd-half B
      #pragma unroll
      for (int ot = 0; ot < 4; ++ot)
        B1[ot] = *reinterpret_cast<const bf16x8*>(
            KtP + ((size_t)((otb + ot) * 8 + ks1) * 64 + lane) * 8);
      // compute even half from B0
      __builtin_amdgcn_s_setprio(1);
      #pragma unroll
      for (int itl = 0; itl < 4; ++itl) {
        int m = itl * 16 + lo;
        int byteoff = m * 512 + ((ks0 * 64 + hi * 16) ^ ((m & 7) << 6));
        bf16x8 Af = *reinterpret_cast<const bf16x8*>(
            reinterpret_cast<char*>(As) + byteoff);
        #pragma unroll
        for (int ot = 0; ot < 4; ++ot)
          acc[itl][ot] = __builtin_amdgcn_mfma_f32_16x16x32_bf16(
              Af, B0[ot], acc[itl][ot], 0, 0, 0);
      }
      __builtin_amdgcn_s_setprio(0);
      // reload even-half B for next pair (dead at kp==3)
      if (kp < 3) {
        #pragma unroll
        for (int ot = 0; ot < 4; ++ot)
          B0[ot] = *reinterpret_cast<const bf16x8*>(
              KtP + ((size_t)((otb + ot) * 8 + ks0 + 2) * 64 + lane) * 8);
      }
      // compute odd half from B1
      __builtin_amdgcn_s_setprio(1);
      #pragma unroll
      for (int itl = 0; itl < 4; ++itl) {
        int m = itl * 16 + lo;
        int byteoff = m * 512 + ((ks1 * 64 + hi * 16) ^ ((m & 7) << 6));
        bf16x8 Af = *reinterpret_cast<const bf16x8*>(
            reinterpret_cast<char*>(As) + byteoff);
        #pragma unroll
        for (int ot = 0; ot < 4; ++ot)
          acc[itl][ot] = __builtin_amdgcn_mfma_f32_16x16x32_bf16(
              Af, B1[ot], acc[itl][ot], 0, 0, 0);
      }
      __builtin_amdgcn_s_setprio(0);
    }

    // epilogue: weights K[i0..i0+3][o(lane)] from KtP packed layout.
    // i0 = h*64+itl*16+hi*4 = kse*32+g*8+e with kse = h*2+(itl>>1),
    // g = (itl&1)*2+(hi>>1), e = (hi&1)*4.
    #pragma unroll
    for (int itl = 0; itl < 4; ++itl) {
      const int kse = h * 2 + (itl >> 1);
      const int g = (itl & 1) * 2 + (hi >> 1);
      const int e = (hi & 1) * 4;
      #pragma unroll
      for (int ot = 0; ot < 4; ++ot) {
        const ushort* wp = KtP +
            ((size_t)((otb + ot) * 8 + kse) * 64 + lo + g * 16) * 8 + e;
        ushort4 wv = *reinterpret_cast<const ushort4*>(wp);
        f32x4 a = acc[itl][ot];
        float s = __uint_as_float((unsigned)wv.x << 16) * a[0]
                + __uint_as_float((unsigned)wv.y << 16) * a[1]
                + __uint_as_float((unsigned)wv.z << 16) * a[2]
                + __uint_as_float((unsigned)wv.w << 16) * a[3];
        s += __shfl_xor(s, 16);
        s += __shfl_xor(s, 32);
        oseg[ot] += s;
      }
    }

    if (lane < 16) {
      #pragma unroll
      for (int ot = 0; ot < 4; ++ot)
        atomicAdd(&out[(size_t)b * 1024 + wob + og * 64 + ot * 16 + lane],
                  oseg[ot]);
    }
  }
}

extern "C" void kernel_launch(void* const* d_in, const int* in_sizes, int n_in,
                              void* d_out, int out_size, void* d_ws, size_t ws_size,
                              hipStream_t stream) {
  const float* A = (const float*)d_in[0];   // (256,256,256) f32
  const float* K = (const float*)d_in[1];   // (256,1024)   f32
  float* out = (float*)d_out;               // (256,1024)   f32
  ushort* KtP = (ushort*)d_ws;              // packed (64,8,64,8) bf16
  hipMemsetAsync(d_out, 0, (size_t)out_size * sizeof(float), stream);
  WV_kconv<<<128, 256, 0, stream>>>(K, KtP);
  WV_main<<<1024, 512, 0, stream>>>(A, KtP, out);
}

// Round 23
// 54.514 us; speedup vs baseline: 1.2526x; 1.0492x over previous
//
#include <hip/hip_runtime.h>
#include <hip/hip_bf16.h>

typedef __attribute__((ext_vector_type(8))) short bf16x8;
typedef __attribute__((ext_vector_type(4))) float f32x4;

__device__ __forceinline__ ushort f2bf(float x) {
  unsigned u = __float_as_uint(x);
  u = (u + 0x7FFFu + ((u >> 16) & 1u)) >> 16;
  return (ushort)u;
}

// Pack K (f32 [256][1024]) into MFMA-fragment order:
// chunk c = (otile 0..63, ks 0..7, lane 0..63); chunk holds 8 bf16:
//   o = otile*16 + (lane&15), k = ks*32 + (lane>>4)*8 + e
__global__ void WV_kconv(const float* __restrict__ K, ushort* __restrict__ KtP) {
  int c = blockIdx.x * 256 + threadIdx.x;  // 0..32767
  int otile = c >> 9, ks = (c >> 6) & 7, lane = c & 63;
  int o = otile * 16 + (lane & 15);
  int kb = ks * 32 + (lane >> 4) * 8;
  bf16x8 w;
  #pragma unroll
  for (int e = 0; e < 8; ++e)
    w[e] = (short)f2bf(K[(size_t)(kb + e) * 1024 + o]);
  *reinterpret_cast<bf16x8*>(KtP + (size_t)c * 8) = w;
}

// Block (b,h): h = i-QUARTER (64 rows) -> 32 KB LDS -> 2 blocks/CU.
// 8 waves; wave owns o-strip of 128 (2 og x 4 ot x 16).
// R23 = R22's copy-free unroll-2 loop, reg-trimmed to <=64 arch VGPRs:
// B-load addresses split into per-lane base (KtL, computed once) +
// wave-uniform chunk offset forced to SGPR via readfirstlane. R22's
// 4-reg overshoot (68 -> 132 total > 128) halved occupancy; this aims
// for 64+64=128 exactly -> 4 waves/SIMD with the copy-free loop.
__global__ __launch_bounds__(512, 2) void WV_main(
    const float* __restrict__ A, const ushort* __restrict__ KtP,
    float* __restrict__ out) {
  __shared__ short As[64 * 256];  // 32 KB
  const int bh = blockIdx.x;
  const int b = bh >> 2, h = bh & 3;
  const float* Ah = A + (size_t)b * 65536 + (size_t)h * 16384;
  const int t = threadIdx.x;

  // ---- stage 64 rows: fp32 -> bf16, swizzle byte ^= (row&7)<<6 ----
  #pragma unroll 1
  for (int it = 0; it < 4; ++it) {
    int c = it * 512 + t;  // chunk of 8 floats
    int m = c >> 5;        // local row 0..63
    int s = c & 31;        // 16B slot within row
    const float4* p = reinterpret_cast<const float4*>(Ah) + c * 2;
    float4 v0 = p[0], v1 = p[1];
    bf16x8 w;
    w[0] = (short)f2bf(v0.x); w[1] = (short)f2bf(v0.y);
    w[2] = (short)f2bf(v0.z); w[3] = (short)f2bf(v0.w);
    w[4] = (short)f2bf(v1.x); w[5] = (short)f2bf(v1.y);
    w[6] = (short)f2bf(v1.z); w[7] = (short)f2bf(v1.w);
    int byteoff = m * 512 + ((s * 16) ^ ((m & 7) << 6));
    *reinterpret_cast<bf16x8*>(reinterpret_cast<char*>(As) + byteoff) = w;
  }
  __syncthreads();

  const int wave = t >> 6, lane = t & 63;
  const int lo = lane & 15;   // col within tile (B,D) / row (A)
  const int hi = lane >> 4;   // 0..3
  const ushort* KtL = KtP + lane * 8;  // per-lane base, computed once

  #pragma unroll 1
  for (int og = 0; og < 2; ++og) {
    float oseg[4] = {0.f, 0.f, 0.f, 0.f};
    const int otb = wave * 8 + og * 4;  // o-tile base (wave-uniform)

    f32x4 acc[4][4];
    #pragma unroll
    for (int a1 = 0; a1 < 4; ++a1)
      #pragma unroll
      for (int a2 = 0; a2 < 4; ++a2)
        acc[a1][a2] = (f32x4){0.f, 0.f, 0.f, 0.f};

    bf16x8 B0[4], B1[4];  // scoped to og
    #pragma unroll
    for (int ot = 0; ot < 4; ++ot)
      B0[ot] = *reinterpret_cast<const bf16x8*>(
          KtL + __builtin_amdgcn_readfirstlane((otb + ot) * 4096));

    #pragma unroll 1
    for (int kp = 0; kp < 4; ++kp) {
      const int ks0 = kp * 2, ks1 = kp * 2 + 1;
      // load odd-half B (SGPR chunk offset + per-lane base)
      #pragma unroll
      for (int ot = 0; ot < 4; ++ot)
        B1[ot] = *reinterpret_cast<const bf16x8*>(
            KtL + __builtin_amdgcn_readfirstlane((otb + ot) * 4096 + ks1 * 512));
      // compute even half from B0
      __builtin_amdgcn_s_setprio(1);
      #pragma unroll
      for (int itl = 0; itl < 4; ++itl) {
        int m = itl * 16 + lo;
        int byteoff = m * 512 + ((ks0 * 64 + hi * 16) ^ ((m & 7) << 6));
        bf16x8 Af = *reinterpret_cast<const bf16x8*>(
            reinterpret_cast<char*>(As) + byteoff);
        #pragma unroll
        for (int ot = 0; ot < 4; ++ot)
          acc[itl][ot] = __builtin_amdgcn_mfma_f32_16x16x32_bf16(
              Af, B0[ot], acc[itl][ot], 0, 0, 0);
      }
      __builtin_amdgcn_s_setprio(0);
      // reload even-half B for next pair (dead at kp==3)
      if (kp < 3) {
        #pragma unroll
        for (int ot = 0; ot < 4; ++ot)
          B0[ot] = *reinterpret_cast<const bf16x8*>(
              KtL + __builtin_amdgcn_readfirstlane((otb + ot) * 4096 +
                                                   (ks0 + 2) * 512));
      }
      // compute odd half from B1
      __builtin_amdgcn_s_setprio(1);
      #pragma unroll
      for (int itl = 0; itl < 4; ++itl) {
        int m = itl * 16 + lo;
        int byteoff = m * 512 + ((ks1 * 64 + hi * 16) ^ ((m & 7) << 6));
        bf16x8 Af = *reinterpret_cast<const bf16x8*>(
            reinterpret_cast<char*>(As) + byteoff);
        #pragma unroll
        for (int ot = 0; ot < 4; ++ot)
          acc[itl][ot] = __builtin_amdgcn_mfma_f32_16x16x32_bf16(
              Af, B1[ot], acc[itl][ot], 0, 0, 0);
      }
      __builtin_amdgcn_s_setprio(0);
    }

    // epilogue: weights K[i0..i0+3][o(lane)] from KtP packed layout.
    // i0 = h*64+itl*16+hi*4 = kse*32+g*8+e with kse = h*2+(itl>>1),
    // g = (itl&1)*2+(hi>>1), e = (hi&1)*4.
    #pragma unroll
    for (int itl = 0; itl < 4; ++itl) {
      const int kse = h * 2 + (itl >> 1);
      const int g = (itl & 1) * 2 + (hi >> 1);
      const int e = (hi & 1) * 4;
      #pragma unroll
      for (int ot = 0; ot < 4; ++ot) {
        const ushort* wp = KtP +
            ((size_t)((otb + ot) * 8 + kse) * 64 + lo + g * 16) * 8 + e;
        ushort4 wv = *reinterpret_cast<const ushort4*>(wp);
        f32x4 a = acc[itl][ot];
        float s = __uint_as_float((unsigned)wv.x << 16) * a[0]
                + __uint_as_float((unsigned)wv.y << 16) * a[1]
                + __uint_as_float((unsigned)wv.z << 16) * a[2]
                + __uint_as_float((unsigned)wv.w << 16) * a[3];
        s += __shfl_xor(s, 16);
        s += __shfl_xor(s, 32);
        oseg[ot] += s;
      }
    }

    if (lane < 16) {
      #pragma unroll
      for (int ot = 0; ot < 4; ++ot)
        atomicAdd(&out[(size_t)b * 1024 + (otb + ot) * 16 + lane], oseg[ot]);
    }
  }
}

extern "C" void kernel_launch(void* const* d_in, const int* in_sizes, int n_in,
                              void* d_out, int out_size, void* d_ws, size_t ws_size,
                              hipStream_t stream) {
  const float* A = (const float*)d_in[0];   // (256,256,256) f32
  const float* K = (const float*)d_in[1];   // (256,1024)   f32
  float* out = (float*)d_out;               // (256,1024)   f32
  ushort* KtP = (ushort*)d_ws;              // packed (64,8,64,8) bf16
  hipMemsetAsync(d_out, 0, (size_t)out_size * sizeof(float), stream);
  WV_kconv<<<128, 256, 0, stream>>>(K, KtP);
  WV_main<<<1024, 512, 0, stream>>>(A, KtP, out);
}